// Round 1
// 286.607 us; speedup vs baseline: 1.0643x; 1.0643x over previous
//
#include <hip/hip_runtime.h>
#include <stdint.h>

#define D_DIM 1024
#define T_DIM 4096
#define B_DIM 4
#define M_DIM 16384
#define NX 16777216UL
#define NW 1048576UL
#define LOG8F 2.0794415416798357f
#define CHUNK_L 64
#define NCHUNK 64
#define WARM 16
#define NT 32

typedef __attribute__((ext_vector_type(4))) float f32x4;
typedef __attribute__((ext_vector_type(8))) short bf16x8;

__device__ __forceinline__ unsigned short f2bf(float f) {
    unsigned u = __float_as_uint(f);
    u += 0x7fffu + ((u >> 16) & 1u);
    return (unsigned short)(u >> 16);
}
__device__ __forceinline__ float unp_lo(unsigned p) { return __uint_as_float(p << 16); }
__device__ __forceinline__ float unp_hi(unsigned p) { return __uint_as_float(p & 0xffff0000u); }
__device__ __forceinline__ float sigm(float x) { return 1.0f / (1.0f + __expf(-x)); }

__device__ __forceinline__ void gl_lds16(const void* g, void* l) {
    __builtin_amdgcn_global_load_lds(
        (const __attribute__((address_space(1))) void*)g,
        (__attribute__((address_space(3))) void*)l, 16, 0, 0);
}

// ---------------------------------------------------------------------------
// Kernel 0: convert x, W_r, W_i, W_x  fp32 -> bf16 (4 elems/thread)
// ---------------------------------------------------------------------------
__global__ __launch_bounds__(256) void cvt_kernel(
    const float* __restrict__ x, const float* __restrict__ Wr,
    const float* __restrict__ Wi, const float* __restrict__ Wx,
    unsigned short* __restrict__ xb, unsigned short* __restrict__ wb)
{
    size_t tid = (size_t)blockIdx.x * 256 + threadIdx.x;
    size_t i = tid * 4;
    const float* src;
    unsigned short* dst;
    size_t off;
    if (i < NX) {
        src = x; dst = xb; off = i;
    } else {
        size_t j = i - NX;
        size_t w = j >> 20;           // / NW
        off = j & (NW - 1);
        src = (w == 0) ? Wr : (w == 1 ? Wi : Wx);
        dst = wb + w * NW;
    }
    float4 v = *(const float4*)(src + off);
    ushort4 o;
    o.x = f2bf(v.x); o.y = f2bf(v.y); o.z = f2bf(v.z); o.w = f2bf(v.w);
    *(ushort4*)(dst + off) = o;
}

// ---------------------------------------------------------------------------
// Kernel 1: single-pass 3-fused GEMM + gating, deep-pipelined.
//   Structural change vs prior session (which was the 2-barrier m97-class
//   structure, latency-bound at ~2400 cy/K-step vs 320 cy of MFMA):
//   - ALL THREE weights in one K-loop: x staged once (was 2x). 8 waves,
//     wave tile 64m x 32d x 3w -> acc[3][4][2] = 96 VGPR.
//   - BK=32, 4-deep circular LDS (4 x 32KB = 128KB), loads issued 3 K-tiles
//     ahead; ONE raw s_barrier per tile with COUNTED s_waitcnt vmcnt(8)
//     (never 0 in the main loop) -> HBM/L3 latency hidden under ~2800 cy of
//     prefetch distance. Tail drains 8 -> 4 -> 0.
//   - XOR-swizzle: gl_lds dest stays linear (HW requires it); the GLOBAL
//     source col-group is inverse-swizzled (cg ^= (row>>1)&3) and ds_read
//     applies the same swizzle -> the 8-way bank conflict of the row-major
//     [128][32] tile (1.05e7 conflict cycles measured) becomes 2-way (free).
//   - s_setprio(1) around the 24-MFMA cluster (phase-split schedule -> T5).
//   - grid map kept: bid&7 = d-tile = XCD -> per-XCD W-slice 768 KB stays
//     L2-resident (prior sessions proved remapping this is a loss).
// ---------------------------------------------------------------------------
__global__ __launch_bounds__(512, 2) void fused_gemm(
    const unsigned short* __restrict__ xb, const unsigned short* __restrict__ wb,
    const float* __restrict__ b_r, const float* __restrict__ b_i,
    unsigned short* __restrict__ a_out, float* __restrict__ u_out)
{
    // [buf 0..3][sub: A,B0,B1,B2][128 rows x 32 k] bf16 = 128 KB
    __shared__ __align__(16) unsigned short lds[4][4][4096];

    const int tid  = threadIdx.x;
    const int lane = tid & 63;
    const int wave = tid >> 6;
    const int wm = wave & 1;            // m-half (64 rows)
    const int wn = wave >> 1;           // d-quarter (32 cols)
    const int m0 = ((int)blockIdx.x >> 3) * 128;
    const int d0 = ((int)blockIdx.x & 7) * 128;
    const int frow = lane & 15;
    const int kgrp = lane >> 4;

    // staging: thread -> LDS slot (row=tid>>2, cg=tid&3); global source
    // col-group inverse-swizzled so swizzled ds_read returns correct data
    const int r0 = tid >> 2;
    const int cgs = (tid & 3) ^ ((r0 >> 1) & 3);
    const unsigned short* srcA = xb + (size_t)(m0 + r0) * D_DIM + cgs * 8;
    const unsigned short* srcB = wb + (size_t)(d0 + r0) * D_DIM + cgs * 8;

    // reader byte offsets (in ushorts), swizzle folded in
    int offA[4], offB[2];
    #pragma unroll
    for (int i = 0; i < 4; i++) {
        const int row = wm * 64 + i * 16 + frow;
        offA[i] = row * 32 + ((kgrp ^ ((row >> 1) & 3)) << 3);
    }
    #pragma unroll
    for (int j = 0; j < 2; j++) {
        const int row = wn * 32 + j * 16 + frow;
        offB[j] = row * 32 + ((kgrp ^ ((row >> 1) & 3)) << 3);
    }

    f32x4 acc[3][4][2];
    #pragma unroll
    for (int w = 0; w < 3; w++)
        #pragma unroll
        for (int i = 0; i < 4; i++)
            #pragma unroll
            for (int j = 0; j < 2; j++) acc[w][i][j] = (f32x4){0.f, 0.f, 0.f, 0.f};

    auto stage = [&](int t) {
        const int buf = t & 3;
        const int k0 = t << 5;
        gl_lds16(srcA + k0, &lds[buf][0][tid * 8]);
        #pragma unroll
        for (int w = 0; w < 3; w++)
            gl_lds16(srcB + (size_t)w * NW + k0, &lds[buf][1 + w][tid * 8]);
    };

    stage(0); stage(1); stage(2);

// one tile: counted-vmcnt wait (own loads for tile t landed; up to VM newer
// loads stay in flight ACROSS the barrier), barrier publishes LDS, issue
// prefetch for t+3, ds_read + 24 MFMA.
#define TILE_BODY(T, VM)                                                      \
    {                                                                         \
        asm volatile("s_waitcnt vmcnt(" #VM ")" ::: "memory");                \
        __builtin_amdgcn_s_barrier();                                         \
        if ((T) + 3 < NT) stage((T) + 3);                                     \
        const int buf = (T) & 3;                                              \
        bf16x8 af[4], bfr[3][2];                                              \
        _Pragma("unroll")                                                     \
        for (int i = 0; i < 4; i++)                                           \
            af[i] = *(const bf16x8*)&lds[buf][0][offA[i]];                    \
        _Pragma("unroll")                                                     \
        for (int w = 0; w < 3; w++)                                           \
            _Pragma("unroll")                                                 \
            for (int j = 0; j < 2; j++)                                       \
                bfr[w][j] = *(const bf16x8*)&lds[buf][1 + w][offB[j]];        \
        __builtin_amdgcn_s_setprio(1);                                        \
        _Pragma("unroll")                                                     \
        for (int w = 0; w < 3; w++)                                           \
            _Pragma("unroll")                                                 \
            for (int i = 0; i < 4; i++)                                       \
                _Pragma("unroll")                                             \
                for (int j = 0; j < 2; j++)                                   \
                    acc[w][i][j] = __builtin_amdgcn_mfma_f32_16x16x32_bf16(   \
                        af[i], bfr[w][j], acc[w][i][j], 0, 0, 0);             \
        __builtin_amdgcn_s_setprio(0);                                        \
    }

    for (int t = 0; t < NT - 3; ++t) TILE_BODY(t, 8);
    TILE_BODY(NT - 3, 8);
    TILE_BODY(NT - 2, 4);
    TILE_BODY(NT - 1, 0);
#undef TILE_BODY

    // Epilogue. C/D layout: col(d) = lane&15, row(m) = (lane>>4)*4 + r.
    const int mb = m0 + wm * 64 + kgrp * 4;
    const int db = d0 + wn * 32 + frow;
    #pragma unroll
    for (int j = 0; j < 2; j++) {
        const int d = db + j * 16;
        const float br = b_r[d];
        const float bi = b_i[d];
        #pragma unroll
        for (int i = 0; i < 4; i++) {
            const int m = mb + i * 16;
            #pragma unroll
            for (int r = 0; r < 4; r++) {
                const size_t idx = (size_t)(m + r) * D_DIM + d;
                float rg = sigm(acc[0][i][j][r] + br);
                // exp(-softplus(z)) == sigmoid(-z);  a in (0.11, 0.5)
                float a = sigm(-LOG8F * rg);
                a_out[idx] = f2bf(a);
                float g = sqrtf(fmaxf(1.0f - a * a, 1e-6f));
                u_out[idx] = g * sigm(acc[1][i][j][r] + bi) * acc[2][i][j][r];
            }
        }
    }
}

// ---------------------------------------------------------------------------
// Kernel 2: chunk-start h via 16-step warm-up (a <= 0.5 => decay >= 1 bit/step,
// so truncation error <= 2^-16 * |h|). 2 d-chains per thread (float2 loads).
// Must stay a separate launch: apply overwrites u in place, warm reads u.
// ---------------------------------------------------------------------------
__global__ __launch_bounds__(256) void scan_warm(
    const unsigned short* __restrict__ a, const float* __restrict__ u,
    const float* __restrict__ h0, float* __restrict__ hstart)
{
    int tid = blockIdx.x * 256 + threadIdx.x;   // (b*NCHUNK + c)*512 + d2
    int d = (tid & 511) << 1;
    int bc = tid >> 9;
    int b = bc >> 6;
    int c = bc & (NCHUNK - 1);
    float hx, hy;
    if (c == 0) {
        float2 h = *(const float2*)(h0 + b * D_DIM + d);
        hx = h.x; hy = h.y;
    } else {
        hx = 0.0f; hy = 0.0f;
        size_t base = ((size_t)b * T_DIM + (size_t)c * CHUNK_L - WARM) * D_DIM + d;
        #pragma unroll 4
        for (int t = 0; t < WARM; t++) {
            size_t idx = base + (size_t)t * D_DIM;
            unsigned ap = *(const unsigned*)(a + idx);
            float2 uv = *(const float2*)(u + idx);
            hx = unp_lo(ap) * hx + uv.x;
            hy = unp_hi(ap) * hy + uv.y;
        }
    }
    *(float2*)(hstart + bc * D_DIM + d) = make_float2(hx, hy);
}

// ---------------------------------------------------------------------------
// Kernel 3: apply — scan each chunk from hstart, overwrite u -> h in place.
// 2 d-chains per thread. Last chunk's thread also writes h_last.
// ---------------------------------------------------------------------------
__global__ __launch_bounds__(256) void scan_apply(
    const unsigned short* __restrict__ a, const float* __restrict__ hstart,
    float* __restrict__ out)
{
    int tid = blockIdx.x * 256 + threadIdx.x;
    int d = (tid & 511) << 1;
    int bc = tid >> 9;
    int b = bc >> 6;
    int c = bc & (NCHUNK - 1);
    size_t base = ((size_t)b * T_DIM + (size_t)c * CHUNK_L) * D_DIM + d;
    float2 h = *(const float2*)(hstart + bc * D_DIM + d);
    float hx = h.x, hy = h.y;
    #pragma unroll 4
    for (int t = 0; t < CHUNK_L; t++) {
        size_t idx = base + (size_t)t * D_DIM;
        unsigned ap = *(const unsigned*)(a + idx);
        float2 uv = *(const float2*)(out + idx);
        hx = unp_lo(ap) * hx + uv.x;
        hy = unp_hi(ap) * hy + uv.y;
        *(float2*)(out + idx) = make_float2(hx, hy);
    }
    if (c == NCHUNK - 1)
        *(float2*)(out + (size_t)M_DIM * D_DIM + b * D_DIM + d) = make_float2(hx, hy);
}

// ---------------------------------------------------------------------------
extern "C" void kernel_launch(void* const* d_in, const int* in_sizes, int n_in,
                              void* d_out, int out_size, void* d_ws, size_t ws_size,
                              hipStream_t stream)
{
    const float* x  = (const float*)d_in[0];
    const float* h0 = (const float*)d_in[1];
    const float* Wr = (const float*)d_in[2];
    const float* br = (const float*)d_in[3];
    const float* Wi = (const float*)d_in[4];
    const float* bi = (const float*)d_in[5];
    const float* Wx = (const float*)d_in[6];
    float* out = (float*)d_out;

    char* ws = (char*)d_ws;
    unsigned short* xb = (unsigned short*)ws;                          // 32 MB
    unsigned short* wb = (unsigned short*)(ws + 33554432);             // 6 MB
    unsigned short* a_buf = (unsigned short*)(ws + 33554432 + 6291456);// 32 MB bf16
    float* hstart = (float*)(ws + 33554432 + 6291456 + 33554432);      // 1 MB

    // 0: fp32 -> bf16 (x and the three weights)
    cvt_kernel<<<19456, 256, 0, stream>>>(x, Wr, Wi, Wx, xb, wb);
    // 1: single-pass 3-fused GEMM + gating. a(bf16) -> ws, u(fp32) -> d_out
    fused_gemm<<<1024, 512, 0, stream>>>(xb, wb, br, bi, a_buf, out);
    // 2: chunk-start h via warm-up (no sequential dependency)
    scan_warm<<<512, 256, 0, stream>>>(a_buf, out, h0, hstart);
    // 3: in-place chunk scan + h_last
    scan_apply<<<512, 256, 0, stream>>>(a_buf, hstart, out);
}

// Round 4
// 282.919 us; speedup vs baseline: 1.0782x; 1.0130x over previous
//
#include <hip/hip_runtime.h>
#include <stdint.h>

#define D_DIM 1024
#define T_DIM 4096
#define B_DIM 4
#define M_DIM 16384
#define NX 16777216UL
#define NW 1048576UL
#define LOG8F 2.0794415416798357f
#define CHUNK_L 64
#define NCHUNK 64
#define WARM 16
#define NT 32

typedef __attribute__((ext_vector_type(4))) float f32x4;
typedef __attribute__((ext_vector_type(8))) short bf16x8;

__device__ __forceinline__ unsigned short f2bf(float f) {
    unsigned u = __float_as_uint(f);
    u += 0x7fffu + ((u >> 16) & 1u);
    return (unsigned short)(u >> 16);
}
__device__ __forceinline__ float unp_lo(unsigned p) { return __uint_as_float(p << 16); }
__device__ __forceinline__ float unp_hi(unsigned p) { return __uint_as_float(p & 0xffff0000u); }
__device__ __forceinline__ float sigm(float x) { return 1.0f / (1.0f + __expf(-x)); }

__device__ __forceinline__ void gl_lds16(const void* g, void* l) {
    __builtin_amdgcn_global_load_lds(
        (const __attribute__((address_space(1))) void*)g,
        (__attribute__((address_space(3))) void*)l, 16, 0, 0);
}

// ---------------------------------------------------------------------------
// Kernel 0: convert x, W_r, W_i, W_x  fp32 -> bf16 (4 elems/thread)
// ---------------------------------------------------------------------------
__global__ __launch_bounds__(256) void cvt_kernel(
    const float* __restrict__ x, const float* __restrict__ Wr,
    const float* __restrict__ Wi, const float* __restrict__ Wx,
    unsigned short* __restrict__ xb, unsigned short* __restrict__ wb)
{
    size_t tid = (size_t)blockIdx.x * 256 + threadIdx.x;
    size_t i = tid * 4;
    const float* src;
    unsigned short* dst;
    size_t off;
    if (i < NX) {
        src = x; dst = xb; off = i;
    } else {
        size_t j = i - NX;
        size_t w = j >> 20;           // / NW
        off = j & (NW - 1);
        src = (w == 0) ? Wr : (w == 1 ? Wi : Wx);
        dst = wb + w * NW;
    }
    float4 v = *(const float4*)(src + off);
    ushort4 o;
    o.x = f2bf(v.x); o.y = f2bf(v.y); o.z = f2bf(v.z); o.w = f2bf(v.w);
    *(ushort4*)(dst + off) = o;
}

// ---------------------------------------------------------------------------
// Kernel 1: single-pass 3-fused GEMM + gating, deep-pipelined, BIG wave tile.
//   R1 post-mortem: 64m x 32d wave tiles were LDS-read-BW bound (112 KB LDS
//   per 3.1 MFLOP-tile = 1340 cy vs 930 cy MFMA). This version doubles
//   arithmetic intensity per LDS byte:
//   - block tile 256m x 128d, 8 waves (2m x 4n), wave tile 128m x 32d.
//     Per K-tile per CU: 6.3 MFLOP (1865 cy matrix) vs 152 KB LDS (1790 cy)
//     -> matrix-bound. acc[3][8][2] = 192 regs in the unified VGPR/AGPR file.
//   - __launch_bounds__(512) with NO min-waves arg: LDS (120 KB) already
//     limits the CU to one 512-thread block (2 waves/SIMD), so a 256-VGPR
//     cap would only force spill without buying occupancy. R2/R3 container
//     failures' sole plausible kernel-side cause was a spill storm under
//     the (512,2) cap; this removes it at zero occupancy cost.
//   - BK=32, 3-deep circular LDS (3 x 40 KB = 120 KB), prefetch 2 tiles
//     ahead; ONE raw s_barrier per tile + counted s_waitcnt vmcnt(5)
//     (next tile's 5 gl_lds stay in flight across the barrier; tail drains 0).
//   - XOR-swizzle kept (R1: conflicts 1.05e7 -> 0): gl_lds dest linear,
//     global source col-group inverse-swizzled (cg ^= (row>>1)&3), ds_read
//     applies the same involution. (row+128) swizzles identically to row
//     (128 = 0 mod 8), so one source base serves both A halves.
//   - s_setprio(1) around each 6-MFMA cluster.
//   - grid map kept: bid&7 = d-tile = XCD -> per-XCD W-slice 768 KB
//     L2-resident (remapping proved a loss in earlier sessions).
// ---------------------------------------------------------------------------
__global__ __launch_bounds__(512) void fused_gemm(
    const unsigned short* __restrict__ xb, const unsigned short* __restrict__ wb,
    const float* __restrict__ b_r, const float* __restrict__ b_i,
    unsigned short* __restrict__ a_out, float* __restrict__ u_out)
{
    // per buffer: A[256][32] = 8192 ush (16 KB) then B[3][128][32] = 12288 ush
    __shared__ __align__(16) unsigned short lds[3][20480];   // 120 KB

    const int tid  = threadIdx.x;
    const int lane = tid & 63;
    const int wave = tid >> 6;
    const int wm = wave & 1;            // m-half (128 rows of 256)
    const int wn = wave >> 1;           // d-quarter (32 cols of 128)
    const int m0 = ((int)blockIdx.x >> 3) * 256;
    const int d0 = ((int)blockIdx.x & 7) * 128;
    const int frow = lane & 15;
    const int kgrp = lane >> 4;

    // staging: thread -> LDS slot (row=tid>>2, cg=tid&3); global source
    // col-group inverse-swizzled so swizzled ds_read returns correct data
    const int r0 = tid >> 2;            // 0..127
    const int cgs = (tid & 3) ^ ((r0 >> 1) & 3);
    const unsigned short* srcA  = xb + (size_t)(m0 + r0) * D_DIM + cgs * 8;
    const unsigned short* srcB0 = wb + (size_t)(d0 + r0) * D_DIM + cgs * 8;
    const unsigned short* srcB1 = srcB0 + NW;
    const unsigned short* srcB2 = srcB0 + 2 * NW;

    // reader offsets (ushort units), swizzle folded in
    int offA[8], offB[3][2];
    #pragma unroll
    for (int i = 0; i < 8; i++) {
        const int row = wm * 128 + i * 16 + frow;
        offA[i] = row * 32 + ((kgrp ^ ((row >> 1) & 3)) << 3);
    }
    #pragma unroll
    for (int w = 0; w < 3; w++)
        #pragma unroll
        for (int j = 0; j < 2; j++) {
            const int row = wn * 32 + j * 16 + frow;
            offB[w][j] = 8192 + w * 4096 + row * 32 + ((kgrp ^ ((row >> 1) & 3)) << 3);
        }

    f32x4 acc[3][8][2];
    #pragma unroll
    for (int w = 0; w < 3; w++)
        #pragma unroll
        for (int i = 0; i < 8; i++)
            #pragma unroll
            for (int j = 0; j < 2; j++) acc[w][i][j] = (f32x4){0.f, 0.f, 0.f, 0.f};

    auto stage = [&](int t) {
        const int buf = t % 3;
        const int k0 = t << 5;
        gl_lds16(srcA  + k0,          &lds[buf][tid * 8]);
        gl_lds16(srcA  + 131072 + k0, &lds[buf][(tid + 512) * 8]);  // rows 128..255
        gl_lds16(srcB0 + k0,          &lds[buf][8192 + tid * 8]);
        gl_lds16(srcB1 + k0,          &lds[buf][12288 + tid * 8]);
        gl_lds16(srcB2 + k0,          &lds[buf][16384 + tid * 8]);
    };

    stage(0); stage(1);

// one tile: counted-vmcnt wait (tile T's 5 loads landed; the next tile's 5
// stay in flight ACROSS the barrier), barrier publishes LDS, prefetch T+2,
// then per-i {1 ds_read + 6 MFMA} with bfr[3][2] preloaded.
#define TILE_BODY(T, VM)                                                      \
    {                                                                         \
        asm volatile("s_waitcnt vmcnt(" #VM ")" ::: "memory");                \
        __builtin_amdgcn_s_barrier();                                         \
        if ((T) + 2 < NT) stage((T) + 2);                                     \
        const int buf = (T) % 3;                                              \
        bf16x8 bfr[3][2];                                                     \
        _Pragma("unroll")                                                     \
        for (int w = 0; w < 3; w++)                                           \
            _Pragma("unroll")                                                 \
            for (int j = 0; j < 2; j++)                                       \
                bfr[w][j] = *(const bf16x8*)&lds[buf][offB[w][j]];            \
        _Pragma("unroll")                                                     \
        for (int i = 0; i < 8; i++) {                                         \
            bf16x8 af = *(const bf16x8*)&lds[buf][offA[i]];                   \
            __builtin_amdgcn_s_setprio(1);                                    \
            _Pragma("unroll")                                                 \
            for (int w = 0; w < 3; w++)                                       \
                _Pragma("unroll")                                             \
                for (int j = 0; j < 2; j++)                                   \
                    acc[w][i][j] = __builtin_amdgcn_mfma_f32_16x16x32_bf16(   \
                        af, bfr[w][j], acc[w][i][j], 0, 0, 0);                \
            __builtin_amdgcn_s_setprio(0);                                    \
        }                                                                     \
    }

    for (int t = 0; t < NT - 1; ++t) TILE_BODY(t, 5);
    TILE_BODY(NT - 1, 0);
#undef TILE_BODY

    // Epilogue. C/D layout: col(d) = lane&15, row(m) = (lane>>4)*4 + r.
    const int mb = m0 + wm * 128 + kgrp * 4;
    const int db = d0 + wn * 32 + frow;
    #pragma unroll
    for (int j = 0; j < 2; j++) {
        const int d = db + j * 16;
        const float br = b_r[d];
        const float bi = b_i[d];
        #pragma unroll
        for (int i = 0; i < 8; i++) {
            const int m = mb + i * 16;
            #pragma unroll
            for (int r = 0; r < 4; r++) {
                const size_t idx = (size_t)(m + r) * D_DIM + d;
                float rg = sigm(acc[0][i][j][r] + br);
                // exp(-softplus(z)) == sigmoid(-z);  a in (0.11, 0.5)
                float a = sigm(-LOG8F * rg);
                a_out[idx] = f2bf(a);
                float g = sqrtf(fmaxf(1.0f - a * a, 1e-6f));
                u_out[idx] = g * sigm(acc[1][i][j][r] + bi) * acc[2][i][j][r];
            }
        }
    }
}

// ---------------------------------------------------------------------------
// Kernel 2: chunk-start h via 16-step warm-up (a <= 0.5 => decay >= 1 bit/step,
// so truncation error <= 2^-16 * |h|). 2 d-chains per thread (float2 loads).
// Must stay a separate launch: apply overwrites u in place, warm reads u.
// ---------------------------------------------------------------------------
__global__ __launch_bounds__(256) void scan_warm(
    const unsigned short* __restrict__ a, const float* __restrict__ u,
    const float* __restrict__ h0, float* __restrict__ hstart)
{
    int tid = blockIdx.x * 256 + threadIdx.x;   // (b*NCHUNK + c)*512 + d2
    int d = (tid & 511) << 1;
    int bc = tid >> 9;
    int b = bc >> 6;
    int c = bc & (NCHUNK - 1);
    float hx, hy;
    if (c == 0) {
        float2 h = *(const float2*)(h0 + b * D_DIM + d);
        hx = h.x; hy = h.y;
    } else {
        hx = 0.0f; hy = 0.0f;
        size_t base = ((size_t)b * T_DIM + (size_t)c * CHUNK_L - WARM) * D_DIM + d;
        #pragma unroll 4
        for (int t = 0; t < WARM; t++) {
            size_t idx = base + (size_t)t * D_DIM;
            unsigned ap = *(const unsigned*)(a + idx);
            float2 uv = *(const float2*)(u + idx);
            hx = unp_lo(ap) * hx + uv.x;
            hy = unp_hi(ap) * hy + uv.y;
        }
    }
    *(float2*)(hstart + bc * D_DIM + d) = make_float2(hx, hy);
}

// ---------------------------------------------------------------------------
// Kernel 3: apply — scan each chunk from hstart, overwrite u -> h in place.
// 2 d-chains per thread. Last chunk's thread also writes h_last.
// ---------------------------------------------------------------------------
__global__ __launch_bounds__(256) void scan_apply(
    const unsigned short* __restrict__ a, const float* __restrict__ hstart,
    float* __restrict__ out)
{
    int tid = blockIdx.x * 256 + threadIdx.x;
    int d = (tid & 511) << 1;
    int bc = tid >> 9;
    int b = bc >> 6;
    int c = bc & (NCHUNK - 1);
    size_t base = ((size_t)b * T_DIM + (size_t)c * CHUNK_L) * D_DIM + d;
    float2 h = *(const float2*)(hstart + bc * D_DIM + d);
    float hx = h.x, hy = h.y;
    #pragma unroll 4
    for (int t = 0; t < CHUNK_L; t++) {
        size_t idx = base + (size_t)t * D_DIM;
        unsigned ap = *(const unsigned*)(a + idx);
        float2 uv = *(const float2*)(out + idx);
        hx = unp_lo(ap) * hx + uv.x;
        hy = unp_hi(ap) * hy + uv.y;
        *(float2*)(out + idx) = make_float2(hx, hy);
    }
    if (c == NCHUNK - 1)
        *(float2*)(out + (size_t)M_DIM * D_DIM + b * D_DIM + d) = make_float2(hx, hy);
}

// ---------------------------------------------------------------------------
extern "C" void kernel_launch(void* const* d_in, const int* in_sizes, int n_in,
                              void* d_out, int out_size, void* d_ws, size_t ws_size,
                              hipStream_t stream)
{
    const float* x  = (const float*)d_in[0];
    const float* h0 = (const float*)d_in[1];
    const float* Wr = (const float*)d_in[2];
    const float* br = (const float*)d_in[3];
    const float* Wi = (const float*)d_in[4];
    const float* bi = (const float*)d_in[5];
    const float* Wx = (const float*)d_in[6];
    float* out = (float*)d_out;

    char* ws = (char*)d_ws;
    unsigned short* xb = (unsigned short*)ws;                          // 32 MB
    unsigned short* wb = (unsigned short*)(ws + 33554432);             // 6 MB
    unsigned short* a_buf = (unsigned short*)(ws + 33554432 + 6291456);// 32 MB bf16
    float* hstart = (float*)(ws + 33554432 + 6291456 + 33554432);      // 1 MB

    // 0: fp32 -> bf16 (x and the three weights)
    cvt_kernel<<<19456, 256, 0, stream>>>(x, Wr, Wi, Wx, xb, wb);
    // 1: single-pass 3-fused GEMM + gating. a(bf16) -> ws, u(fp32) -> d_out
    fused_gemm<<<512, 512, 0, stream>>>(xb, wb, br, bi, a_buf, out);
    // 2: chunk-start h via warm-up (no sequential dependency)
    scan_warm<<<512, 256, 0, stream>>>(a_buf, out, h0, hstart);
    // 3: in-place chunk scan + h_last
    scan_apply<<<512, 256, 0, stream>>>(a_buf, hstart, out);
}